// Round 12
// baseline (166.680 us; speedup 1.0000x reference)
//
#include <hip/hip_runtime.h>
#include <math.h>

#define ROWLEN 16384
#define BLOCK  512
#define NCHUNK 8              // 8 x float4 = 32 floats / thread; 512*32 = 16384
#define NWAVE  (BLOCK / 64)
#define NMOM   9              // central moments p = 2..10
#define EPSV   1e-10
#define RPB    16             // rows per block
#define NBLOCKS (8192 / RPB)  // 512 blocks = 2 per CU (LDS-capped)

typedef float f32x2 __attribute__((ext_vector_type(2)));

__device__ __forceinline__ f32x2 pk_mul(f32x2 a, f32x2 b)
{
    f32x2 d;
    asm("v_pk_mul_f32 %0, %1, %2" : "=v"(d) : "v"(a), "v"(b));
    return d;
}

// lgkm-only workgroup barrier (R8-proven): does NOT drain vmcnt, so the
// background row DMA stays in flight across reductions.
__device__ __forceinline__ void sync_lds()
{
    asm volatile("s_waitcnt lgkmcnt(0)" ::: "memory");
    __builtin_amdgcn_s_barrier();
    asm volatile("" ::: "memory");
}

// Async global->LDS DMA, 16B/lane (R8-proven correct).
__device__ __forceinline__ void gload_lds16(const float* gsrc, float* ldst)
{
    __builtin_amdgcn_global_load_lds(
        (const __attribute__((address_space(1))) void*)gsrc,
        (__attribute__((address_space(3))) void*)ldst, 16, 0, 0);
}

// Compute on registers (row r) while row r+1 DMAs into LDS in the background:
// HBM feed is decoupled from the block's compute phases (the R10 structure's
// residual 21us was blocks' feed stopping during their compute phases).
// 2 blocks/CU x 8 waves = same 16 waves/CU as R10.
__global__ __launch_bounds__(BLOCK, 4) void moments_kernel(
    const float* __restrict__ y, float* __restrict__ out)
{
    const int tid  = threadIdx.x;
    const int wave = tid >> 6;
    const int lane = tid & 63;
    const int row0 = blockIdx.x * RPB;

    __shared__ float buf[ROWLEN];          // 64 KB single staging buffer
    __shared__ double wsum[NWAVE];
    __shared__ double wacc[NWAVE][NMOM];

    // Each wave DMAs its contiguous 8 KB stripe as 8 x 1 KB instructions.
    auto issue = [&](int row) {
        const float* src = y + (size_t)row * ROWLEN;
        const int stripe = wave * (ROWLEN / NWAVE);        // floats
#pragma unroll
        for (int i = 0; i < 8; ++i) {
            const int off = stripe + i * 256;              // 256 floats = 1 KB
            gload_lds16(src + off + lane * 4, buf + off);
        }
    };

    issue(row0);                                           // prologue DMA

#pragma unroll 1
    for (int r = 0; r < RPB; ++r) {
        const int row = row0 + r;

        // row r's DMA complete in LDS (all waves)
        asm volatile("s_waitcnt vmcnt(0)" ::: "memory");
        __builtin_amdgcn_s_barrier();
        asm volatile("" ::: "memory");

        // LDS -> registers (ds_read_b128), then free the buffer
        float4 v[NCHUNK];
        const float4* b4 = reinterpret_cast<const float4*>(buf);
#pragma unroll
        for (int i = 0; i < NCHUNK; ++i)
            v[i] = b4[i * BLOCK + tid];
        sync_lds();                        // all waves done reading buf

        if (r + 1 < RPB) issue(row + 1);   // background DMA for next row

        // ---- phase 1: mean (R3-proven 512-thread mapping) ----
        double tsum = 0.0;
#pragma unroll
        for (int i = 0; i < NCHUNK; ++i) {
            float s = (v[i].x + v[i].y) + (v[i].z + v[i].w);
            tsum += (double)s;
        }
#pragma unroll
        for (int off = 32; off > 0; off >>= 1)
            tsum += __shfl_xor(tsum, off, 64);
        if (lane == 0) wsum[wave] = tsum;
        sync_lds();

        double total = 0.0;
#pragma unroll
        for (int w = 0; w < NWAVE; ++w) total += wsum[w];
        const double meand = total * (1.0 / (double)ROWLEN);
        const float  meanf = (float)meand;

        // ---- phase 2: packed chains, f64 flush per float4 (R11-proven) ----
        double acc[NMOM];
#pragma unroll
        for (int p = 0; p < NMOM; ++p) acc[p] = 0.0;

#pragma unroll
        for (int i = 0; i < NCHUNK; ++i) {
            const float4 c = v[i];
            const f32x2 za = { c.x - meanf, c.y - meanf };
            const f32x2 zb = { c.z - meanf, c.w - meanf };
            f32x2 pa = pk_mul(za, za);              // z^2
            f32x2 pb = pk_mul(zb, zb);
            acc[0] += (double)((pa.x + pa.y) + (pb.x + pb.y));
#pragma unroll
            for (int p = 1; p < NMOM; ++p) {
                pa = pk_mul(pa, za);                // z^(p+2)
                pb = pk_mul(pb, zb);
                acc[p] += (double)((pa.x + pa.y) + (pb.x + pb.y));
            }
        }

#pragma unroll
        for (int p = 0; p < NMOM; ++p) {
#pragma unroll
            for (int off = 32; off > 0; off >>= 1)
                acc[p] += __shfl_xor(acc[p], off, 64);
        }
        if (lane == 0) {
#pragma unroll
            for (int p = 0; p < NMOM; ++p) wacc[wave][p] = acc[p];
        }
        sync_lds();

        // ---- epilogue: lanes 0..9 in parallel (R10-proven) ----
        if (tid < 10) {
            const double N = (double)ROWLEN;
            float* o = out + (size_t)row * 10;

            double s2 = 0.0;
#pragma unroll
            for (int w = 0; w < NWAVE; ++w) s2 += wacc[w][0];
            const double stdv = sqrt(s2 / (N - 1.0)) + EPSV;

            if (tid == 0) {
                const double sg0 = (meand > 0.0) ? 1.0 : (meand < 0.0 ? -1.0 : 0.0);
                o[0] = (float)sg0 * logf((float)(fabs(meand) + EPSV));
            } else {
                const int p = tid - 1;
                double s = 0.0;
#pragma unroll
                for (int w = 0; w < NWAVE; ++w) s += wacc[w][p];

                double sp = stdv;                  // std^1
                for (int k = 0; k <= p; ++k) sp *= stdv;   // std^(p+2)

                const double cm  = s / N;
                const double nrm = cm / (sp + EPSV);
                const double sg  = (nrm > 0.0) ? 1.0 : (nrm < 0.0 ? -1.0 : 0.0);
                float mj = (float)sg * logf((float)(fabs(nrm) + EPSV));
                mj = fminf(10.0f, fmaxf(-10.0f, mj));
                o[tid] = mj;
            }
        }
        // NOTE: no barrier needed here; next iteration's vmcnt(0)+barrier
        // orders everything, and wsum/wacc are parity-safe because every
        // reuse is preceded by a sync_lds.
    }
}

extern "C" void kernel_launch(void* const* d_in, const int* in_sizes, int n_in,
                              void* d_out, int out_size, void* d_ws, size_t ws_size,
                              hipStream_t stream)
{
    const float* y = (const float*)d_in[0];
    float* out = (float*)d_out;
    const int B = in_sizes[0] / ROWLEN;   // 8192 rows
    moments_kernel<<<B / RPB, BLOCK, 0, stream>>>(y, out);
}

// Round 13
// 124.697 us; speedup vs baseline: 1.3367x; 1.3367x over previous
//
#include <hip/hip_runtime.h>
#include <math.h>

#define ROWLEN 16384
#define BLOCK  512
#define NCHUNK 8              // 8 x float4 = 32 floats / thread; 512*32 = 16384
#define NWAVE  (BLOCK / 64)
#define NMOM   9              // central moments p = 2..10
#define EPSV   1e-10

typedef float f32x2 __attribute__((ext_vector_type(2)));

// VOP3P packed fp32: 2 elements per instruction.
__device__ __forceinline__ f32x2 pk_mul(f32x2 a, f32x2 b)
{
    f32x2 d;
    asm("v_pk_mul_f32 %0, %1, %2" : "=v"(d) : "v"(a), "v"(b));
    return d;
}

// R10's proven structure taken to FULL wave occupancy: 512-thread blocks with
// the lean R11 math (packed chains + per-float4 f64 flush ~ 62-66 VGPR) under
// a 64-VGPR cap -> 8 waves/SIMD -> 4 blocks/CU -> 32 waves/CU (2x R10's 16).
// Same 4-block phase diversity, twice the TLP to keep loads outstanding.
__global__ __launch_bounds__(BLOCK, 8) void moments_kernel(
    const float* __restrict__ y, float* __restrict__ out)
{
    const int row  = blockIdx.x;
    const int tid  = threadIdx.x;
    const int wave = tid >> 6;
    const int lane = tid & 63;

    const float4* yrow = reinterpret_cast<const float4*>(y + (size_t)row * ROWLEN);

    // ---- single HBM read: keep the whole row in registers ----
    float4 v[NCHUNK];
#pragma unroll
    for (int i = 0; i < NCHUNK; ++i)
        v[i] = yrow[i * BLOCK + tid];

    // ---- phase 1: mean (R3-proven 512-thread mapping) ----
    double tsum = 0.0;
#pragma unroll
    for (int i = 0; i < NCHUNK; ++i) {
        float s = (v[i].x + v[i].y) + (v[i].z + v[i].w);
        tsum += (double)s;
    }
#pragma unroll
    for (int off = 32; off > 0; off >>= 1)
        tsum += __shfl_xor(tsum, off, 64);

    __shared__ double wsum[NWAVE];
    if (lane == 0) wsum[wave] = tsum;
    __syncthreads();

    double total = 0.0;
#pragma unroll
    for (int w = 0; w < NWAVE; ++w) total += wsum[w];

    const double meand = total * (1.0 / (double)ROWLEN);
    const float  meanf = (float)meand;

    // ---- phase 2: packed chains, f64 flush per float4 (R11-proven) ----
    double acc[NMOM];
#pragma unroll
    for (int p = 0; p < NMOM; ++p) acc[p] = 0.0;

#pragma unroll
    for (int i = 0; i < NCHUNK; ++i) {
        const float4 c = v[i];
        const f32x2 za = { c.x - meanf, c.y - meanf };
        const f32x2 zb = { c.z - meanf, c.w - meanf };
        f32x2 pa = pk_mul(za, za);              // z^2
        f32x2 pb = pk_mul(zb, zb);
        acc[0] += (double)((pa.x + pa.y) + (pb.x + pb.y));
#pragma unroll
        for (int p = 1; p < NMOM; ++p) {
            pa = pk_mul(pa, za);                // z^(p+2)
            pb = pk_mul(pb, zb);
            acc[p] += (double)((pa.x + pa.y) + (pb.x + pb.y));
        }
    }

    // ---- wave reduce each accumulator ----
#pragma unroll
    for (int p = 0; p < NMOM; ++p) {
#pragma unroll
        for (int off = 32; off > 0; off >>= 1)
            acc[p] += __shfl_xor(acc[p], off, 64);
    }

    __shared__ double wacc[NWAVE][NMOM];
    if (lane == 0) {
#pragma unroll
        for (int p = 0; p < NMOM; ++p) wacc[wave][p] = acc[p];
    }
    __syncthreads();

    // ---- epilogue: lanes 0..9 in parallel, one output each (R10-proven) ----
    if (tid < 10) {
        const double N = (double)ROWLEN;
        float* o = out + (size_t)row * 10;

        double s2 = 0.0;
#pragma unroll
        for (int w = 0; w < NWAVE; ++w) s2 += wacc[w][0];
        const double stdv = sqrt(s2 / (N - 1.0)) + EPSV;

        if (tid == 0) {
            // m0: signed log of |mean|, NOT clipped
            const double sg0 = (meand > 0.0) ? 1.0 : (meand < 0.0 ? -1.0 : 0.0);
            o[0] = (float)sg0 * logf((float)(fabs(meand) + EPSV));
        } else {
            const int p = tid - 1;             // moment index 0..8 (orders 2..10)
            double s = 0.0;
#pragma unroll
            for (int w = 0; w < NWAVE; ++w) s += wacc[w][p];

            double sp = stdv;                  // std^1
            for (int k = 0; k <= p; ++k) sp *= stdv;   // std^(p+2)

            const double cm  = s / N;
            const double nrm = cm / (sp + EPSV);
            const double sg  = (nrm > 0.0) ? 1.0 : (nrm < 0.0 ? -1.0 : 0.0);
            float mj = (float)sg * logf((float)(fabs(nrm) + EPSV));
            mj = fminf(10.0f, fmaxf(-10.0f, mj));
            o[tid] = mj;
        }
    }
}

extern "C" void kernel_launch(void* const* d_in, const int* in_sizes, int n_in,
                              void* d_out, int out_size, void* d_ws, size_t ws_size,
                              hipStream_t stream)
{
    const float* y = (const float*)d_in[0];
    float* out = (float*)d_out;
    const int B = in_sizes[0] / ROWLEN;   // 8192 rows
    moments_kernel<<<B, BLOCK, 0, stream>>>(y, out);
}

// Round 14
// 101.497 us; speedup vs baseline: 1.6422x; 1.2286x over previous
//
#include <hip/hip_runtime.h>
#include <math.h>

#define ROWLEN 16384
#define BLOCK  256
#define NCHUNK 16             // 16 x float4 = 64 floats / thread; 256*64 = 16384
#define NWAVE  (BLOCK / 64)
#define NMOM   9              // central moments p = 2..10
#define EPSV   1e-10

typedef float f32x2 __attribute__((ext_vector_type(2)));

// VOP3P packed fp32: 2 elements per instruction (gfx90a+, present on gfx950).
__device__ __forceinline__ f32x2 pk_mul(f32x2 a, f32x2 b)
{
    f32x2 d;
    asm("v_pk_mul_f32 %0, %1, %2" : "=v"(d) : "v"(a), "v"(b));
    return d;
}
__device__ __forceinline__ f32x2 pk_add(f32x2 a, f32x2 b)
{
    f32x2 d;
    asm("v_pk_add_f32 %0, %1, %2" : "=v"(d) : "v"(a), "v"(b));
    return d;
}

// SESSION OPTIMUM (round 10, 102.7us): 256-thread blocks, 4 blocks/CU
// (the measured occupancy-U minimum: 2blk=162, 4blk=102.7, 5cap=108,
// 8blk=124.7), register row-cache (single HBM pass), packed-f32 power
// chains with 8-element f64 flush, parallel 10-lane f32-log epilogue.
// All structural alternatives measured worse: deep SW pipeline 198,
// L2 re-read 157, LDS-DMA staging 269/167.
__global__ __launch_bounds__(BLOCK, 4) void moments_kernel(
    const float* __restrict__ y, float* __restrict__ out)
{
    const int row  = blockIdx.x;
    const int tid  = threadIdx.x;
    const int wave = tid >> 6;
    const int lane = tid & 63;

    const float4* yrow = reinterpret_cast<const float4*>(y + (size_t)row * ROWLEN);

    // ---- single HBM read: keep the whole row in registers ----
    float4 v[NCHUNK];
#pragma unroll
    for (int i = 0; i < NCHUNK; ++i)
        v[i] = yrow[i * BLOCK + tid];

    // ---- phase 1: mean ----
    double tsum = 0.0;
#pragma unroll
    for (int i = 0; i < NCHUNK; ++i) {
        float s = (v[i].x + v[i].y) + (v[i].z + v[i].w);
        tsum += (double)s;
    }
#pragma unroll
    for (int off = 32; off > 0; off >>= 1)
        tsum += __shfl_xor(tsum, off, 64);

    __shared__ double wsum[NWAVE];
    if (lane == 0) wsum[wave] = tsum;
    __syncthreads();

    double total = 0.0;
#pragma unroll
    for (int w = 0; w < NWAVE; ++w) total += wsum[w];

    const double meand = total * (1.0 / (double)ROWLEN);
    const float  meanf = (float)meand;

    // ---- phase 2: central power sums p=2..10, packed-f32 chains ----
    double acc[NMOM];
#pragma unroll
    for (int p = 0; p < NMOM; ++p) acc[p] = 0.0;

#pragma unroll
    for (int i = 0; i < NCHUNK; i += 2) {
        f32x2 part[NMOM];
#pragma unroll
        for (int p = 0; p < NMOM; ++p) part[p] = (f32x2){0.0f, 0.0f};

#pragma unroll
        for (int j = 0; j < 2; ++j) {
            const float4 c = v[i + j];
            const f32x2 za = { c.x - meanf, c.y - meanf };
            const f32x2 zb = { c.z - meanf, c.w - meanf };
            f32x2 pa = pk_mul(za, za);          // z^2
            f32x2 pb = pk_mul(zb, zb);
            part[0] = pk_add(part[0], pa);
            part[0] = pk_add(part[0], pb);
#pragma unroll
            for (int p = 1; p < NMOM; ++p) {
                pa = pk_mul(pa, za);            // z^(p+2)
                pb = pk_mul(pb, zb);
                part[p] = pk_add(part[p], pa);
                part[p] = pk_add(part[p], pb);
            }
        }
        // flush 8-element fp32 partials into f64 accumulators
#pragma unroll
        for (int p = 0; p < NMOM; ++p)
            acc[p] += (double)(part[p].x + part[p].y);
    }

    // ---- wave reduce each accumulator ----
#pragma unroll
    for (int p = 0; p < NMOM; ++p) {
#pragma unroll
        for (int off = 32; off > 0; off >>= 1)
            acc[p] += __shfl_xor(acc[p], off, 64);
    }

    __shared__ double wacc[NWAVE][NMOM];
    if (lane == 0) {
#pragma unroll
        for (int p = 0; p < NMOM; ++p) wacc[wave][p] = acc[p];
    }
    __syncthreads();

    // ---- epilogue: lanes 0..9 in parallel, one output each ----
    if (tid < 10) {
        const double N = (double)ROWLEN;
        float* o = out + (size_t)row * 10;

        double s2 = 0.0;
#pragma unroll
        for (int w = 0; w < NWAVE; ++w) s2 += wacc[w][0];
        const double stdv = sqrt(s2 / (N - 1.0)) + EPSV;

        if (tid == 0) {
            // m0: signed log of |mean|, NOT clipped
            const double sg0 = (meand > 0.0) ? 1.0 : (meand < 0.0 ? -1.0 : 0.0);
            o[0] = (float)sg0 * logf((float)(fabs(meand) + EPSV));
        } else {
            const int p = tid - 1;             // moment index 0..8 (orders 2..10)
            double s = 0.0;
#pragma unroll
            for (int w = 0; w < NWAVE; ++w) s += wacc[w][p];

            double sp = stdv;                  // std^1
            for (int k = 0; k <= p; ++k) sp *= stdv;   // std^(p+2)

            const double cm  = s / N;
            const double nrm = cm / (sp + EPSV);
            const double sg  = (nrm > 0.0) ? 1.0 : (nrm < 0.0 ? -1.0 : 0.0);
            float mj = (float)sg * logf((float)(fabs(nrm) + EPSV));
            mj = fminf(10.0f, fmaxf(-10.0f, mj));
            o[tid] = mj;
        }
    }
}

extern "C" void kernel_launch(void* const* d_in, const int* in_sizes, int n_in,
                              void* d_out, int out_size, void* d_ws, size_t ws_size,
                              hipStream_t stream)
{
    const float* y = (const float*)d_in[0];
    float* out = (float*)d_out;
    const int B = in_sizes[0] / ROWLEN;   // 8192 rows
    moments_kernel<<<B, BLOCK, 0, stream>>>(y, out);
}